// Round 2
// baseline (607.237 us; speedup 1.0000x reference)
//
#include <hip/hip_runtime.h>

#define BATCH 8
#define PN    16384
#define NSAMP 256
#define KDIM  512
#define HID   384
#define HALF  192
#define CIN   576   // HID + HALF
#define ROWS  2048  // BATCH * NSAMP
#define BN_EPS 1e-5f

// workspace offsets (in floats); total 1949696 floats = 7.8 MB
#define OFF_GF   0
#define OFF_W1T  3072
#define OFF_W2T  224256
#define OFF_IDX  371712   /* 2048 ints */
#define OFF_H1   373760
#define OFF_H2   1160192
#define OFF_SUM1 1946624
#define OFF_SQ1  1947008
#define OFF_SUM2 1947392
#define OFF_SQ2  1947776
#define OFF_SC1  1948160
#define OFF_SH1  1948544
#define OFF_SC2  1948928
#define OFF_SH2  1949312

// ---------------- K1: prep: global_feat, W1^T, W2^T, zero BN sums ----------
__global__ __launch_bounds__(256) void k_prep(const float* pf,
                                              const float* Wf,
                                              const float* bfe,
                                              const float* W1,
                                              const float* W2,
                                              float* ws) {
  __shared__ float s[KDIM];
  int blk = blockIdx.x, t = threadIdx.x;
  if (blk < 8) {                     // global_feat[b] = pf[b] @ W_feat + b_feat
    for (int k = t; k < KDIM; k += 256) s[k] = pf[blk * KDIM + k];
    __syncthreads();
    for (int o = t; o < HID; o += 256) {
      float acc = bfe[o];
      for (int k = 0; k < KDIM; k++) acc = fmaf(s[k], Wf[k * HID + o], acc);
      ws[OFF_GF + blk * HID + o] = acc;
    }
  } else if (blk < 16) {             // W1t[c][o] = W1[o][c]
    for (int sI = (blk - 8) * 256 + t; sI < HID * CIN; sI += 2048) {
      int o = sI / CIN, c = sI % CIN;
      ws[OFF_W1T + c * HID + o] = W1[sI];
    }
  } else if (blk < 24) {             // W2t[c][o] = W2[o][c]
    for (int sI = (blk - 16) * 256 + t; sI < HID * HID; sI += 2048) {
      int o = sI / HID, c = sI % HID;
      ws[OFF_W2T + c * HID + o] = W2[sI];
    }
  } else {                           // zero sum1/sq1/sum2/sq2 (contiguous 1536)
    for (int i = t; i < 1536; i += 256) ws[OFF_SUM1 + i] = 0.f;
  }
}

// ---------------- K2: farthest point sampling (Mahalanobis rank-3 trick) ----
// FPS on 192-dim local_feat == FPS on 3-dim p under metric G = Wc Wc^T = L L^T.
// d(i,j) = || L^T p_i - L^T p_j ||^2 ; q = L^T p precomputed once per point.
__global__ __launch_bounds__(1024, 1) void k_fps(const float* p,
                                                 const float* Wc,
                                                 int* idx_out) {
  int b = blockIdx.x, t = threadIdx.x;
  __shared__ float Msh[6];
  __shared__ unsigned long long red[16];
  __shared__ int far_sh;

  // G (3x3) in fp64 + Cholesky, wave 0 only
  if (t < 64) {
    double g0 = 0, g1 = 0, g2 = 0, g3 = 0, g4 = 0, g5 = 0;
    for (int k = t; k < HALF; k += 64) {
      double w0 = (double)Wc[k];
      double w1 = (double)Wc[HALF + k];
      double w2 = (double)Wc[2 * HALF + k];
      g0 += w0 * w0; g1 += w0 * w1; g2 += w0 * w2;
      g3 += w1 * w1; g4 += w1 * w2; g5 += w2 * w2;
    }
    for (int off = 32; off; off >>= 1) {
      g0 += __shfl_down(g0, off, 64); g1 += __shfl_down(g1, off, 64);
      g2 += __shfl_down(g2, off, 64); g3 += __shfl_down(g3, off, 64);
      g4 += __shfl_down(g4, off, 64); g5 += __shfl_down(g5, off, 64);
    }
    if (t == 0) {
      double l00 = sqrt(g0);
      double l10 = g1 / l00, l20 = g2 / l00;
      double l11 = sqrt(g3 - l10 * l10);
      double l21 = (g4 - l10 * l20) / l11;
      double l22 = sqrt(g5 - l20 * l20 - l21 * l21);
      Msh[0] = (float)l00; Msh[1] = (float)l10; Msh[2] = (float)l20;
      Msh[3] = (float)l11; Msh[4] = (float)l21; Msh[5] = (float)l22;
    }
  }
  __syncthreads();
  float m00 = Msh[0], m10 = Msh[1], m20 = Msh[2];
  float m11 = Msh[3], m21 = Msh[4], m22 = Msh[5];

  const float* pb = p + b * PN * 3;
  float qx[16], qy[16], qz[16], dist[16];
#pragma unroll
  for (int j = 0; j < 16; j++) {
    int i = (j << 10) + t;            // strided ownership: i = j*1024 + t
    float x = pb[i * 3], y = pb[i * 3 + 1], z = pb[i * 3 + 2];
    qx[j] = fmaf(m00, x, fmaf(m10, y, m20 * z));
    qy[j] = fmaf(m11, y, m21 * z);
    qz[j] = m22 * z;
    dist[j] = 1e10f;
  }

  int far = 0;
  for (int k = 0; k < NSAMP; k++) {
    if (t == 0) idx_out[b * NSAMP + k] = far;   // scan emits pre-update far
    float x = pb[far * 3], y = pb[far * 3 + 1], z = pb[far * 3 + 2];
    float cx = fmaf(m00, x, fmaf(m10, y, m20 * z));
    float cy = fmaf(m11, y, m21 * z);
    float cz = m22 * z;
    float bv = -1.f; unsigned bj = 0;
#pragma unroll
    for (int j = 0; j < 16; j++) {
      float dx = qx[j] - cx, dy = qy[j] - cy, dz = qz[j] - cz;
      float d  = fmaf(dx, dx, fmaf(dy, dy, dz * dz));
      float nd = fminf(dist[j], d);
      dist[j] = nd;
      bool gt = nd > bv;                        // strict > : first-index tiebreak
      bv = gt ? nd : bv;
      bj = gt ? (unsigned)j : bj;
    }
    unsigned bi = (bj << 10) + (unsigned)t;
    // pack: larger dist wins; equal dist -> smaller global index wins (~bi)
    unsigned long long key =
        (((unsigned long long)__float_as_uint(bv)) << 32) | (unsigned)(~bi);
#pragma unroll
    for (int off = 32; off; off >>= 1) {
      unsigned long long o = __shfl_xor(key, off, 64);
      key = (o > key) ? o : key;
    }
    if ((t & 63) == 0) red[t >> 6] = key;
    __syncthreads();
    if (t < 64) {
      unsigned long long k2 = (t < 16) ? red[t] : 0ull;
#pragma unroll
      for (int off = 8; off; off >>= 1) {
        unsigned long long o = __shfl_xor(k2, off, 64);
        k2 = (o > k2) ? o : k2;
      }
      if (t == 0) far_sh = (int)(~((unsigned)k2));
    }
    __syncthreads();
    far = far_sh;
  }
}

// ---------------- K3: GEMM1 (fused gather of combined) + bias + BN1 sums ----
__global__ __launch_bounds__(384) void k_gemm1(const float* p,
                                               const float* Wc,
                                               const float* bc,
                                               const float* b1,
                                               float* ws) {
  __shared__ __align__(16) float ct[CIN * 8];
  int t = threadIdx.x;
  int row0 = blockIdx.x * 8;
  const int* fidx = (const int*)(ws + OFF_IDX);
  // stage combined tile [8 rows][576] transposed: ct[c*8+r]
  for (int s = t; s < 8 * CIN; s += 384) {
    int r = s / CIN, c = s % CIN;
    int row = row0 + r, b = row >> 8;
    float val;
    if (c < HID) {
      val = ws[OFF_GF + b * HID + c];                // broadcast global_feat
    } else {
      int co = c - HID;
      int i = fidx[row];
      const float* pp = p + (b * PN + i) * 3;
      float x = pp[0], y = pp[1], z = pp[2];
      val = bc[co];
      val = fmaf(x, Wc[co], val);
      val = fmaf(y, Wc[HALF + co], val);
      val = fmaf(z, Wc[2 * HALF + co], val);         // sampled local_feat
    }
    ct[c * 8 + r] = val;
  }
  __syncthreads();
  const float* w1t = ws + OFF_W1T;
  float acc[8] = {0.f, 0.f, 0.f, 0.f, 0.f, 0.f, 0.f, 0.f};
  for (int c = 0; c < CIN; c++) {
    float w = w1t[c * HID + t];
    float4 a0 = *(const float4*)(ct + c * 8);
    float4 a1 = *(const float4*)(ct + c * 8 + 4);
    acc[0] = fmaf(a0.x, w, acc[0]); acc[1] = fmaf(a0.y, w, acc[1]);
    acc[2] = fmaf(a0.z, w, acc[2]); acc[3] = fmaf(a0.w, w, acc[3]);
    acc[4] = fmaf(a1.x, w, acc[4]); acc[5] = fmaf(a1.y, w, acc[5]);
    acc[6] = fmaf(a1.z, w, acc[6]); acc[7] = fmaf(a1.w, w, acc[7]);
  }
  float bias = b1[t];
  float sv = 0.f, sq = 0.f;
#pragma unroll
  for (int r = 0; r < 8; r++) {
    float v = acc[r] + bias;
    ws[OFF_H1 + (row0 + r) * HID + t] = v;
    sv += v; sq = fmaf(v, v, sq);
  }
  atomicAdd(&ws[OFF_SUM1 + t], sv);
  atomicAdd(&ws[OFF_SQ1 + t], sq);
}

// ---------------- BN finalize: scale/shift from sums ----------------------
__global__ __launch_bounds__(384) void k_bnfin(const float* g,
                                               const float* be,
                                               float* ws, int sum_off,
                                               int sc_off) {
  int t = threadIdx.x;
  float m = ws[sum_off + t] * (1.f / ROWS);
  float v = ws[sum_off + 384 + t] * (1.f / ROWS) - m * m;
  float inv = 1.f / sqrtf(v + BN_EPS);
  float sc = inv * g[t];
  ws[sc_off + t] = sc;
  ws[sc_off + 384 + t] = be[t] - m * sc;
}

// ---------------- K4: GEMM2 with fused BN1-affine + ReLU on load ----------
__global__ __launch_bounds__(384) void k_gemm2(const float* b2,
                                               float* ws) {
  __shared__ __align__(16) float ht[HID * 8];
  int t = threadIdx.x;
  int row0 = blockIdx.x * 8;
  const float* sc1 = ws + OFF_SC1;
  const float* sh1 = ws + OFF_SH1;
  for (int s = t; s < 8 * HID; s += 384) {
    int r = s / HID, c = s % HID;
    float x = fmaf(ws[OFF_H1 + (row0 + r) * HID + c], sc1[c], sh1[c]);
    ht[c * 8 + r] = fmaxf(x, 0.f);
  }
  __syncthreads();
  const float* w2t = ws + OFF_W2T;
  float acc[8] = {0.f, 0.f, 0.f, 0.f, 0.f, 0.f, 0.f, 0.f};
  for (int c = 0; c < HID; c++) {
    float w = w2t[c * HID + t];
    float4 a0 = *(const float4*)(ht + c * 8);
    float4 a1 = *(const float4*)(ht + c * 8 + 4);
    acc[0] = fmaf(a0.x, w, acc[0]); acc[1] = fmaf(a0.y, w, acc[1]);
    acc[2] = fmaf(a0.z, w, acc[2]); acc[3] = fmaf(a0.w, w, acc[3]);
    acc[4] = fmaf(a1.x, w, acc[4]); acc[5] = fmaf(a1.y, w, acc[5]);
    acc[6] = fmaf(a1.z, w, acc[6]); acc[7] = fmaf(a1.w, w, acc[7]);
  }
  float bias = b2[t];
  float sv = 0.f, sq = 0.f;
#pragma unroll
  for (int r = 0; r < 8; r++) {
    float v = acc[r] + bias;
    ws[OFF_H2 + (row0 + r) * HID + t] = v;
    sv += v; sq = fmaf(v, v, sq);
  }
  atomicAdd(&ws[OFF_SUM2 + t], sv);
  atomicAdd(&ws[OFF_SQ2 + t], sq);
}

// ---------------- K5: BN2 affine + ReLU --------------------------------
__global__ __launch_bounds__(256) void k_out(const float* ws, float* out) {
  int gid = blockIdx.x * 256 + threadIdx.x;
  int i = gid * 4;
  float4 h = *(const float4*)(ws + OFF_H2 + i);
  int c = i % HID;
  float4 sc = *(const float4*)(ws + OFF_SC2 + c);
  float4 sh = *(const float4*)(ws + OFF_SH2 + c);
  float4 r;
  r.x = fmaxf(fmaf(h.x, sc.x, sh.x), 0.f);
  r.y = fmaxf(fmaf(h.y, sc.y, sh.y), 0.f);
  r.z = fmaxf(fmaf(h.z, sc.z, sh.z), 0.f);
  r.w = fmaxf(fmaf(h.w, sc.w, sh.w), 0.f);
  ((float4*)out)[gid] = r;
}

extern "C" void kernel_launch(void* const* d_in, const int* in_sizes, int n_in,
                              void* d_out, int out_size, void* d_ws, size_t ws_size,
                              hipStream_t stream) {
  const float* p   = (const float*)d_in[0];
  // d_in[1] = N (int scalar, always 256)
  const float* pf  = (const float*)d_in[2];
  const float* Wf  = (const float*)d_in[3];
  const float* bfe = (const float*)d_in[4];
  const float* Wc  = (const float*)d_in[5];
  const float* bc  = (const float*)d_in[6];
  const float* W1  = (const float*)d_in[7];
  const float* b1  = (const float*)d_in[8];
  const float* g1  = (const float*)d_in[9];
  const float* be1 = (const float*)d_in[10];
  const float* W2  = (const float*)d_in[11];
  const float* b2  = (const float*)d_in[12];
  const float* g2  = (const float*)d_in[13];
  const float* be2 = (const float*)d_in[14];
  float* ws = (float*)d_ws;

  hipLaunchKernelGGL(k_prep, dim3(25), dim3(256), 0, stream, pf, Wf, bfe, W1, W2, ws);
  hipLaunchKernelGGL(k_fps, dim3(8), dim3(1024), 0, stream, p, Wc, (int*)(ws + OFF_IDX));
  hipLaunchKernelGGL(k_gemm1, dim3(256), dim3(384), 0, stream, p, Wc, bc, b1, ws);
  hipLaunchKernelGGL(k_bnfin, dim3(1), dim3(384), 0, stream, g1, be1, ws, OFF_SUM1, OFF_SC1);
  hipLaunchKernelGGL(k_gemm2, dim3(256), dim3(384), 0, stream, b2, ws);
  hipLaunchKernelGGL(k_bnfin, dim3(1), dim3(384), 0, stream, g2, be2, ws, OFF_SUM2, OFF_SC2);
  hipLaunchKernelGGL(k_out, dim3(768), dim3(256), 0, stream, ws, (float*)d_out);
}

// Round 3
// 599.906 us; speedup vs baseline: 1.0122x; 1.0122x over previous
//
#include <hip/hip_runtime.h>

#define BATCH 8
#define PN    16384
#define NSAMP 256
#define KDIM  512
#define HID   384
#define HALF  192
#define CIN   576   // HID + HALF
#define ROWS  2048  // BATCH * NSAMP
#define BN_EPS 1e-5f

// workspace offsets (in floats)
#define OFF_GF   0
#define OFF_W1T  3072
#define OFF_W2T  224256
#define OFF_IDX  371712   /* 2048 ints */
#define OFF_H1   373760
#define OFF_H2   1160192
#define OFF_SUM1 1946624
#define OFF_SQ1  1947008
#define OFF_SUM2 1947392
#define OFF_SQ2  1947776

// ---- K1: fused FPS (blocks 0..7) + prep (blocks 8..32) --------------------
// FPS on 192-dim local_feat == FPS on 3-dim p under metric G = Wc Wc^T = LL^T.
// d(i,j) = ||L^T p_i - L^T p_j||^2 ; q = L^T p precomputed per point.
// Distance math + packed-key tie-break identical to the passing R2 version.
__global__ __launch_bounds__(1024) void k_main(const float* p, const float* Wc,
                                               const float* pf, const float* Wf,
                                               const float* bfe, const float* W1,
                                               const float* W2, float* ws) {
  __shared__ float s[KDIM];
  __shared__ float Msh[6];
  __shared__ unsigned long long red[2][16];
  int blk = blockIdx.x, t = threadIdx.x;

  if (blk >= 8) {                    // ---- prep work, hidden under FPS ----
    if (blk < 16) {                  // W1t[c][o] = W1[o][c]
      for (int sI = (blk - 8) * 1024 + t; sI < HID * CIN; sI += 8192) {
        int o = sI / CIN, c = sI % CIN;
        ws[OFF_W1T + c * HID + o] = W1[sI];
      }
    } else if (blk < 24) {           // W2t[c][o] = W2[o][c]
      for (int sI = (blk - 16) * 1024 + t; sI < HID * HID; sI += 8192) {
        int o = sI / HID, c = sI % HID;
        ws[OFF_W2T + c * HID + o] = W2[sI];
      }
    } else if (blk < 32) {           // global_feat[b] = pf[b] @ W_feat + b_feat
      int b = blk - 24;
      if (t < KDIM) s[t] = pf[b * KDIM + t];
      __syncthreads();
      if (t < HID) {
        float acc = bfe[t];
        for (int k = 0; k < KDIM; k++) acc = fmaf(s[k], Wf[k * HID + t], acc);
        ws[OFF_GF + b * HID + t] = acc;
      }
    } else {                         // zero BN sums (contiguous 1536 floats)
      for (int i = t; i < 1536; i += 1024) ws[OFF_SUM1 + i] = 0.f;
    }
    return;
  }

  // ---- FPS, one batch per block ----
  int b = blk;
  int* idx_out = (int*)(ws + OFF_IDX);

  if (t < 64) {                      // G (3x3) in fp64 + Cholesky, wave 0
    double g0 = 0, g1 = 0, g2 = 0, g3 = 0, g4 = 0, g5 = 0;
    for (int k = t; k < HALF; k += 64) {
      double w0 = (double)Wc[k];
      double w1 = (double)Wc[HALF + k];
      double w2 = (double)Wc[2 * HALF + k];
      g0 += w0 * w0; g1 += w0 * w1; g2 += w0 * w2;
      g3 += w1 * w1; g4 += w1 * w2; g5 += w2 * w2;
    }
    for (int off = 32; off; off >>= 1) {
      g0 += __shfl_down(g0, off, 64); g1 += __shfl_down(g1, off, 64);
      g2 += __shfl_down(g2, off, 64); g3 += __shfl_down(g3, off, 64);
      g4 += __shfl_down(g4, off, 64); g5 += __shfl_down(g5, off, 64);
    }
    if (t == 0) {
      double l00 = sqrt(g0);
      double l10 = g1 / l00, l20 = g2 / l00;
      double l11 = sqrt(g3 - l10 * l10);
      double l21 = (g4 - l10 * l20) / l11;
      double l22 = sqrt(g5 - l20 * l20 - l21 * l21);
      Msh[0] = (float)l00; Msh[1] = (float)l10; Msh[2] = (float)l20;
      Msh[3] = (float)l11; Msh[4] = (float)l21; Msh[5] = (float)l22;
    }
  }
  __syncthreads();
  float m00 = Msh[0], m10 = Msh[1], m20 = Msh[2];
  float m11 = Msh[3], m21 = Msh[4], m22 = Msh[5];

  const float* pb = p + b * PN * 3;
  float qx[16], qy[16], qz[16], dist[16];
#pragma unroll
  for (int j = 0; j < 16; j++) {
    int i = (j << 10) + t;           // strided ownership: i = j*1024 + t
    float x = pb[i * 3], y = pb[i * 3 + 1], z = pb[i * 3 + 2];
    qx[j] = fmaf(m00, x, fmaf(m10, y, m20 * z));
    qy[j] = fmaf(m11, y, m21 * z);
    qz[j] = m22 * z;
    dist[j] = 1e10f;
  }

  int far = 0, par = 0;
  for (int k = 0; k < NSAMP; k++) {
    if (t == 0) idx_out[b * NSAMP + k] = far;  // scan emits pre-update far
    float x = pb[far * 3], y = pb[far * 3 + 1], z = pb[far * 3 + 2];
    float cx = fmaf(m00, x, fmaf(m10, y, m20 * z));
    float cy = fmaf(m11, y, m21 * z);
    float cz = m22 * z;
    float bv = -1.f; unsigned bj = 0;
#pragma unroll
    for (int j = 0; j < 16; j++) {
      float dx = qx[j] - cx, dy = qy[j] - cy, dz = qz[j] - cz;
      float d  = fmaf(dx, dx, fmaf(dy, dy, dz * dz));
      float nd = fminf(dist[j], d);
      dist[j] = nd;
      bool gt = nd > bv;                       // strict > : first-index tiebreak
      bv = gt ? nd : bv;
      bj = gt ? (unsigned)j : bj;
    }
    unsigned bi = (bj << 10) + (unsigned)t;
    // pack: larger dist wins; equal dist -> smaller global index wins (~bi)
    unsigned long long key =
        (((unsigned long long)__float_as_uint(bv)) << 32) | (unsigned)(~bi);
#pragma unroll
    for (int off = 32; off; off >>= 1) {
      unsigned long long o = __shfl_xor(key, off, 64);
      key = (o > key) ? o : key;
    }
    if ((t & 63) == 0) red[par][t >> 6] = key;
    __syncthreads();                            // the ONLY barrier per step
    unsigned long long best = red[par][0];
#pragma unroll
    for (int w = 1; w < 16; w++) {              // all threads reduce 16 keys
      unsigned long long o = red[par][w];
      best = (o > best) ? o : best;
    }
    far = (int)(~((unsigned)best));
    par ^= 1;                                   // double-buffer: no 2nd barrier
  }
}

// ---- K2: GEMM1 (fused gather of combined) + bias + BN1 sums --------------
__global__ __launch_bounds__(384) void k_gemm1(const float* p,
                                               const float* Wc,
                                               const float* bc,
                                               const float* b1,
                                               float* ws) {
  __shared__ __align__(16) float ct[CIN * 8];
  int t = threadIdx.x;
  int row0 = blockIdx.x * 8;
  const int* fidx = (const int*)(ws + OFF_IDX);
  for (int sI = t; sI < 8 * CIN; sI += 384) {  // stage tile transposed ct[c*8+r]
    int r = sI / CIN, c = sI % CIN;
    int row = row0 + r, b = row >> 8;
    float val;
    if (c < HID) {
      val = ws[OFF_GF + b * HID + c];          // broadcast global_feat
    } else {
      int co = c - HID;
      int i = fidx[row];
      const float* pp = p + (b * PN + i) * 3;
      val = bc[co];
      val = fmaf(pp[0], Wc[co], val);
      val = fmaf(pp[1], Wc[HALF + co], val);
      val = fmaf(pp[2], Wc[2 * HALF + co], val);  // sampled local_feat
    }
    ct[c * 8 + r] = val;
  }
  __syncthreads();
  const float* w1t = ws + OFF_W1T;
  float acc[8] = {0.f, 0.f, 0.f, 0.f, 0.f, 0.f, 0.f, 0.f};
  for (int c = 0; c < CIN; c++) {
    float w = w1t[c * HID + t];
    float4 a0 = *(const float4*)(ct + c * 8);
    float4 a1 = *(const float4*)(ct + c * 8 + 4);
    acc[0] = fmaf(a0.x, w, acc[0]); acc[1] = fmaf(a0.y, w, acc[1]);
    acc[2] = fmaf(a0.z, w, acc[2]); acc[3] = fmaf(a0.w, w, acc[3]);
    acc[4] = fmaf(a1.x, w, acc[4]); acc[5] = fmaf(a1.y, w, acc[5]);
    acc[6] = fmaf(a1.z, w, acc[6]); acc[7] = fmaf(a1.w, w, acc[7]);
  }
  float bias = b1[t];
  float sv = 0.f, sq = 0.f;
#pragma unroll
  for (int r = 0; r < 8; r++) {
    float v = acc[r] + bias;
    ws[OFF_H1 + (row0 + r) * HID + t] = v;
    sv += v; sq = fmaf(v, v, sq);
  }
  atomicAdd(&ws[OFF_SUM1 + t], sv);
  atomicAdd(&ws[OFF_SQ1 + t], sq);
}

// ---- K3: GEMM2 with inline BN1 finalize + ReLU on load -------------------
__global__ __launch_bounds__(384) void k_gemm2(const float* b2,
                                               const float* g1,
                                               const float* be1,
                                               float* ws) {
  __shared__ __align__(16) float ht[HID * 8];
  __shared__ float sc1s[HID], sh1s[HID];
  int t = threadIdx.x;
  int row0 = blockIdx.x * 8;
  {                                   // BN1 finalize, redundantly per block
    float m = ws[OFF_SUM1 + t] * (1.f / ROWS);
    float v = ws[OFF_SQ1 + t] * (1.f / ROWS) - m * m;
    float inv = 1.f / sqrtf(v + BN_EPS);
    float sc = inv * g1[t];
    sc1s[t] = sc;
    sh1s[t] = be1[t] - m * sc;
  }
  __syncthreads();
  for (int sI = t; sI < 8 * HID; sI += 384) {
    int r = sI / HID, c = sI % HID;
    float x = fmaf(ws[OFF_H1 + (row0 + r) * HID + c], sc1s[c], sh1s[c]);
    ht[c * 8 + r] = fmaxf(x, 0.f);
  }
  __syncthreads();
  const float* w2t = ws + OFF_W2T;
  float acc[8] = {0.f, 0.f, 0.f, 0.f, 0.f, 0.f, 0.f, 0.f};
  for (int c = 0; c < HID; c++) {
    float w = w2t[c * HID + t];
    float4 a0 = *(const float4*)(ht + c * 8);
    float4 a1 = *(const float4*)(ht + c * 8 + 4);
    acc[0] = fmaf(a0.x, w, acc[0]); acc[1] = fmaf(a0.y, w, acc[1]);
    acc[2] = fmaf(a0.z, w, acc[2]); acc[3] = fmaf(a0.w, w, acc[3]);
    acc[4] = fmaf(a1.x, w, acc[4]); acc[5] = fmaf(a1.y, w, acc[5]);
    acc[6] = fmaf(a1.z, w, acc[6]); acc[7] = fmaf(a1.w, w, acc[7]);
  }
  float bias = b2[t];
  float sv = 0.f, sq = 0.f;
#pragma unroll
  for (int r = 0; r < 8; r++) {
    float v = acc[r] + bias;
    ws[OFF_H2 + (row0 + r) * HID + t] = v;
    sv += v; sq = fmaf(v, v, sq);
  }
  atomicAdd(&ws[OFF_SUM2 + t], sv);
  atomicAdd(&ws[OFF_SQ2 + t], sq);
}

// ---- K4: inline BN2 finalize + affine + ReLU -----------------------------
__global__ __launch_bounds__(256) void k_out(const float* ws, const float* g2,
                                             const float* be2, float* out) {
  int gid = blockIdx.x * 256 + threadIdx.x;
  int i = gid * 4;
  int c = i % HID;                    // multiple of 4
  float4 h  = *(const float4*)(ws + OFF_H2 + i);
  float4 s2 = *(const float4*)(ws + OFF_SUM2 + c);
  float4 q2 = *(const float4*)(ws + OFF_SQ2 + c);
  float4 gv = *(const float4*)(g2 + c);
  float4 bv = *(const float4*)(be2 + c);
  float4 r;
#define BN2(comp) {                                                  \
    float m  = s2.comp * (1.f / ROWS);                               \
    float v  = q2.comp * (1.f / ROWS) - m * m;                       \
    float sc = (1.f / sqrtf(v + BN_EPS)) * gv.comp;                  \
    float sh = bv.comp - m * sc;                                     \
    r.comp = fmaxf(fmaf(h.comp, sc, sh), 0.f); }
  BN2(x) BN2(y) BN2(z) BN2(w)
#undef BN2
  ((float4*)out)[gid] = r;
}

extern "C" void kernel_launch(void* const* d_in, const int* in_sizes, int n_in,
                              void* d_out, int out_size, void* d_ws, size_t ws_size,
                              hipStream_t stream) {
  const float* p   = (const float*)d_in[0];
  // d_in[1] = N (int scalar, always 256)
  const float* pf  = (const float*)d_in[2];
  const float* Wf  = (const float*)d_in[3];
  const float* bfe = (const float*)d_in[4];
  const float* Wc  = (const float*)d_in[5];
  const float* bc  = (const float*)d_in[6];
  const float* W1  = (const float*)d_in[7];
  const float* b1  = (const float*)d_in[8];
  const float* g1  = (const float*)d_in[9];
  const float* be1 = (const float*)d_in[10];
  const float* W2  = (const float*)d_in[11];
  const float* b2  = (const float*)d_in[12];
  const float* g2  = (const float*)d_in[13];
  const float* be2 = (const float*)d_in[14];
  float* ws = (float*)d_ws;

  hipLaunchKernelGGL(k_main,  dim3(33),  dim3(1024), 0, stream,
                     p, Wc, pf, Wf, bfe, W1, W2, ws);
  hipLaunchKernelGGL(k_gemm1, dim3(256), dim3(384), 0, stream, p, Wc, bc, b1, ws);
  hipLaunchKernelGGL(k_gemm2, dim3(256), dim3(384), 0, stream, b2, g1, be1, ws);
  hipLaunchKernelGGL(k_out,   dim3(768), dim3(256), 0, stream,
                     ws, g2, be2, (float*)d_out);
}